// Round 6
// baseline (136.918 us; speedup 1.0000x reference)
//
#include <hip/hip_runtime.h>
#include <math.h>

#define NB 4096
#define KN 64
#define DIM 128
#define HP 132   // LDS pitch (bf16): 264B/row

typedef __bf16 bf16;
typedef bf16 bf16x8 __attribute__((ext_vector_type(8)));
typedef bf16 bf16x4 __attribute__((ext_vector_type(4)));
typedef float f32x4 __attribute__((ext_vector_type(4)));

// w1T[j][i] = w1[i][j]  (128 x 256 bf16), w2T[j2][j1] = w2[j1][j2] (128 x 128)
__global__ void prep_weights(const float* __restrict__ w1,
                             const float* __restrict__ w2,
                             bf16* __restrict__ w1T,
                             bf16* __restrict__ w2T) {
    int t = blockIdx.x * 256 + threadIdx.x;
    if (t < 128 * 256) {
        int j = t >> 8, i = t & 255;
        w1T[t] = (bf16)w1[i * 128 + j];
    } else {
        int t2 = t - 128 * 256;
        int j2 = t2 >> 7, j1 = t2 & 127;
        w2T[t2] = (bf16)w2[j1 * 128 + j2];
    }
}

__global__ __launch_bounds__(256, 4) void graphsage_mfma(
    const int* __restrict__ node_idx,
    const int* __restrict__ neigh_idx,
    const int* __restrict__ neigh_len,
    const float* __restrict__ emb_v,
    const float* __restrict__ emb_t,
    const bf16* __restrict__ w1T,
    const float* __restrict__ b1,
    const bf16* __restrict__ w2T,
    const float* __restrict__ b2,
    const float* __restrict__ w3,
    float* __restrict__ out)
{
    __shared__ bf16  n_lds[KN][HP];      // 16896 B
    __shared__ bf16  h1_lds[KN][HP];     // 16896 B
    __shared__ float scratch[4][DIM];    // 2048 B: score partials / agg partials
    __shared__ float att_lds[KN];        // 256 B
    __shared__ int   ni_lds[KN];         // 256 B
    __shared__ bf16  u_bf[2][DIM];       // 512 B
    // ~36.9 KB -> 4 blocks/CU

    const int b   = blockIdx.x;
    const int tid = threadIdx.x;
    const int len = neigh_len[b];
    const int nd  = node_idx[b];

    // ---- pre-phase: passthrough both modalities; len==0 fallback; u_bf ----
    {
        int mp = tid >> 7, j = tid & 127;
        const float* emb = mp ? emb_t : emb_v;
        float uv = emb[(size_t)nd * DIM + j];
        out[((size_t)mp * NB + b) * DIM + j] = uv;
        if (len == 0)
            out[((size_t)(2 + mp) * NB + b) * DIM + j] = uv;
        else
            u_bf[mp][j] = (bf16)uv;
    }
    if (len == 0) return;   // block-uniform
    if (tid < KN) ni_lds[tid] = neigh_idx[b * KN + tid];
    __syncthreads();   // B0

    const int wv = tid >> 6;
    const int ll = tid & 15;
    const int lh = (tid >> 4) & 3;
    const int nkt = (len + 15) >> 4;   // 1..4, block-uniform
    const int lim = nkt * 16;

    for (int m = 0; m < 2; ++m) {
        const float* __restrict__ emb = m ? emb_t : emb_v;

        // ---- bulk gather: valid neighbor rows -> bf16 LDS (zero-fill pad) ----
        for (int c = tid; c < lim * 16; c += 256) {
            int r = c >> 4, c8 = c & 15;
            bf16x8 v;
            if (r < len) {
                const float* src = emb + (size_t)ni_lds[r] * DIM + c8 * 8;
                float4 f0 = ((const float4*)src)[0];
                float4 f1 = ((const float4*)src)[1];
                v[0] = (bf16)f0.x; v[1] = (bf16)f0.y; v[2] = (bf16)f0.z; v[3] = (bf16)f0.w;
                v[4] = (bf16)f1.x; v[5] = (bf16)f1.y; v[6] = (bf16)f1.z; v[7] = (bf16)f1.w;
            } else {
                #pragma unroll
                for (int q = 0; q < 8; ++q) v[q] = (bf16)0.f;
            }
            *(bf16x8*)&n_lds[r][c8 * 8] = v;
        }
        __syncthreads();   // B1: n_lds ready

        // ---- GEMM1 (j-split): H1^T = W1^T @ [N | u]^T, bias+u in acc-init, relu ----
        {
            // accu = b1 + (W1bot @ u): broadcast-B MFMA, identical across cols
            float4 b1q0 = *(const float4*)(b1 + wv * 32 + lh * 4);
            float4 b1q1 = *(const float4*)(b1 + wv * 32 + 16 + lh * 4);
            f32x4 accu0 = {b1q0.x, b1q0.y, b1q0.z, b1q0.w};
            f32x4 accu1 = {b1q1.x, b1q1.y, b1q1.z, b1q1.w};
            #pragma unroll
            for (int ks = 0; ks < 4; ++ks) {
                bf16x8 bu = *(const bf16x8*)&u_bf[m][ks * 32 + lh * 8];
                bf16x8 a0 = *(const bf16x8*)(w1T + (size_t)(wv * 32 + ll) * 256 + 128 + ks * 32 + lh * 8);
                bf16x8 a1 = *(const bf16x8*)(w1T + (size_t)(wv * 32 + 16 + ll) * 256 + 128 + ks * 32 + lh * 8);
                accu0 = __builtin_amdgcn_mfma_f32_16x16x32_bf16(a0, bu, accu0, 0, 0, 0);
                accu1 = __builtin_amdgcn_mfma_f32_16x16x32_bf16(a1, bu, accu1, 0, 0, 0);
            }

            bf16x8 af0[4], af1[4];
            #pragma unroll
            for (int ks = 0; ks < 4; ++ks) {
                af0[ks] = *(const bf16x8*)(w1T + (size_t)(wv * 32 + ll) * 256 + ks * 32 + lh * 8);
                af1[ks] = *(const bf16x8*)(w1T + (size_t)(wv * 32 + 16 + ll) * 256 + ks * 32 + lh * 8);
            }

            #pragma unroll
            for (int kt = 0; kt < 4; ++kt) {
                if (kt < nkt) {
                    bf16x8 bfr[4];
                    #pragma unroll
                    for (int ks = 0; ks < 4; ++ks)
                        bfr[ks] = *(const bf16x8*)&n_lds[kt * 16 + ll][ks * 32 + lh * 8];
                    f32x4 a0 = accu0, a1 = accu1;
                    #pragma unroll
                    for (int ks = 0; ks < 4; ++ks) {
                        a0 = __builtin_amdgcn_mfma_f32_16x16x32_bf16(af0[ks], bfr[ks], a0, 0, 0, 0);
                        a1 = __builtin_amdgcn_mfma_f32_16x16x32_bf16(af1[ks], bfr[ks], a1, 0, 0, 0);
                    }
                    bf16x4 h0, h1v;
                    #pragma unroll
                    for (int r = 0; r < 4; ++r) {
                        h0[r]  = (bf16)fmaxf(a0[r], 0.f);
                        h1v[r] = (bf16)fmaxf(a1[r], 0.f);
                    }
                    *(bf16x4*)&h1_lds[kt * 16 + ll][wv * 32 + lh * 4]      = h0;
                    *(bf16x4*)&h1_lds[kt * 16 + ll][wv * 32 + 16 + lh * 4] = h1v;
                }
            }
        }
        __syncthreads();   // B2: h1 ready

        // ---- GEMM2 (j2-split): bias in acc-init, fused relu+score partials ----
        {
            bf16x8 af20[4], af21[4];
            #pragma unroll
            for (int ks = 0; ks < 4; ++ks) {
                af20[ks] = *(const bf16x8*)(w2T + (size_t)(wv * 32 + ll) * 128 + ks * 32 + lh * 8);
                af21[ks] = *(const bf16x8*)(w2T + (size_t)(wv * 32 + 16 + ll) * 128 + ks * 32 + lh * 8);
            }
            float4 w3a = *(const float4*)(w3 + wv * 32 + lh * 4);
            float4 w3b = *(const float4*)(w3 + wv * 32 + 16 + lh * 4);
            float w3q0[4] = {w3a.x, w3a.y, w3a.z, w3a.w};
            float w3q1[4] = {w3b.x, w3b.y, w3b.z, w3b.w};
            float4 b2a = *(const float4*)(b2 + wv * 32 + lh * 4);
            float4 b2b = *(const float4*)(b2 + wv * 32 + 16 + lh * 4);

            #pragma unroll
            for (int ntk = 0; ntk < 4; ++ntk) {
                if (ntk < nkt) {
                    bf16x8 bfr[4];
                    #pragma unroll
                    for (int ks = 0; ks < 4; ++ks)
                        bfr[ks] = *(const bf16x8*)&h1_lds[ntk * 16 + ll][ks * 32 + lh * 8];
                    f32x4 c0 = {b2a.x, b2a.y, b2a.z, b2a.w};
                    f32x4 c1 = {b2b.x, b2b.y, b2b.z, b2b.w};
                    #pragma unroll
                    for (int ks = 0; ks < 4; ++ks) {
                        c0 = __builtin_amdgcn_mfma_f32_16x16x32_bf16(af20[ks], bfr[ks], c0, 0, 0, 0);
                        c1 = __builtin_amdgcn_mfma_f32_16x16x32_bf16(af21[ks], bfr[ks], c1, 0, 0, 0);
                    }
                    float s = 0.f;
                    #pragma unroll
                    for (int r = 0; r < 4; ++r) {
                        s = fmaf(fmaxf(c0[r], 0.f), w3q0[r], s);
                        s = fmaf(fmaxf(c1[r], 0.f), w3q1[r], s);
                    }
                    s += __shfl_xor(s, 16);
                    s += __shfl_xor(s, 32);
                    if (lh == 0) scratch[wv][ntk * 16 + ll] = s;
                }
            }
        }
        __syncthreads();   // B3: score partials ready

        // ---- masked softmax over neighbors (wave 0) ----
        if (tid < KN) {
            float s = scratch[0][tid] + scratch[1][tid] + scratch[2][tid] + scratch[3][tid];
            float sv = (tid < len) ? s : -INFINITY;
            float mx = sv;
            #pragma unroll
            for (int off = 1; off < 64; off <<= 1) mx = fmaxf(mx, __shfl_xor(mx, off));
            float e = (tid < len) ? __expf(sv - mx) : 0.f;
            float sum = e;
            #pragma unroll
            for (int off = 1; off < 64; off <<= 1) sum += __shfl_xor(sum, off);
            att_lds[tid] = e / sum;
        }
        __syncthreads();   // B4: att ready

        // ---- aggregate: agg[j] = sum_{k<len} att[k] * N[k][j] ----
        {
            int jg = tid & 31, ks = tid >> 5;   // per wave: ks in {2w, 2w+1}
            int j0 = jg * 4;
            float ax = 0.f, ay = 0.f, az = 0.f, aw = 0.f;
            int kb = ks * 8, ke = min(len, kb + 8);
            for (int k = kb; k < ke; ++k) {
                float av = att_lds[k];
                bf16x4 nv = *(const bf16x4*)&n_lds[k][j0];
                ax = fmaf(av, (float)nv[0], ax);
                ay = fmaf(av, (float)nv[1], ay);
                az = fmaf(av, (float)nv[2], az);
                aw = fmaf(av, (float)nv[3], aw);
            }
            ax += __shfl_xor(ax, 32);
            ay += __shfl_xor(ay, 32);
            az += __shfl_xor(az, 32);
            aw += __shfl_xor(aw, 32);
            if ((tid & 63) < 32) {
                float4 v4 = {ax, ay, az, aw};
                *(float4*)&scratch[wv][j0] = v4;
            }
        }
        __syncthreads();   // B5: agg partials ready
        if (tid < DIM)
            out[((size_t)(2 + m) * NB + b) * DIM + tid] =
                scratch[0][tid] + scratch[1][tid] + scratch[2][tid] + scratch[3][tid];
        __syncthreads();   // B6: protect n_lds/scratch before next modality
    }
}

extern "C" void kernel_launch(void* const* d_in, const int* in_sizes, int n_in,
                              void* d_out, int out_size, void* d_ws, size_t ws_size,
                              hipStream_t stream) {
    const int*   node_idx  = (const int*)d_in[0];
    const int*   neigh_idx = (const int*)d_in[1];
    const int*   neigh_len = (const int*)d_in[2];
    const float* emb_v     = (const float*)d_in[3];
    const float* emb_t     = (const float*)d_in[4];
    const float* w1        = (const float*)d_in[5];
    const float* b1        = (const float*)d_in[6];
    const float* w2        = (const float*)d_in[7];
    const float* b2        = (const float*)d_in[8];
    const float* w3        = (const float*)d_in[9];
    float* out = (float*)d_out;

    bf16* w1T = (bf16*)d_ws;                 // 128*256 bf16 = 64 KiB
    bf16* w2T = (bf16*)d_ws + 128 * 256;     // 128*128 bf16 = 32 KiB

    hipLaunchKernelGGL(prep_weights, dim3(192), dim3(256), 0, stream, w1, w2, w1T, w2T);
    hipLaunchKernelGGL(graphsage_mfma, dim3(NB), dim3(256), 0, stream,
                       node_idx, neigh_idx, neigh_len, emb_v, emb_t,
                       w1T, b1, w2T, b2, w3, out);
}

// Round 7
// 119.575 us; speedup vs baseline: 1.1450x; 1.1450x over previous
//
#include <hip/hip_runtime.h>
#include <math.h>

#define NB 4096
#define KN 64
#define DIM 128
#define HP 132   // LDS pitch (bf16): 264B/row

typedef __bf16 bf16;
typedef bf16 bf16x8 __attribute__((ext_vector_type(8)));
typedef bf16 bf16x4 __attribute__((ext_vector_type(4)));
typedef float f32x4 __attribute__((ext_vector_type(4)));

// w1T[j][i] = w1[i][j]  (128 x 256 bf16), w2T[j2][j1] = w2[j1][j2] (128 x 128)
__global__ void prep_weights(const float* __restrict__ w1,
                             const float* __restrict__ w2,
                             bf16* __restrict__ w1T,
                             bf16* __restrict__ w2T) {
    int t = blockIdx.x * 256 + threadIdx.x;
    if (t < 128 * 256) {
        int j = t >> 8, i = t & 255;
        w1T[t] = (bf16)w1[i * 128 + j];
    } else {
        int t2 = t - 128 * 256;
        int j2 = t2 >> 7, j1 = t2 & 127;
        w2T[t2] = (bf16)w2[j1 * 128 + j2];
    }
}

// one block per (b, modality)
__global__ __launch_bounds__(256, 4) void graphsage_mfma(
    const int* __restrict__ node_idx,
    const int* __restrict__ neigh_idx,
    const int* __restrict__ neigh_len,
    const float* __restrict__ emb_v,
    const float* __restrict__ emb_t,
    const bf16* __restrict__ w1T,
    const float* __restrict__ b1,
    const bf16* __restrict__ w2T,
    const float* __restrict__ b2,
    const float* __restrict__ w3,
    float* __restrict__ out)
{
    __shared__ bf16  n_lds[KN][HP];      // 16896 B
    __shared__ bf16  h1_lds[KN][HP];     // 16896 B
    __shared__ float u_lds[DIM];         // 512 B
    __shared__ float part_lds[2][DIM];   // 1024 B (uq halves)
    __shared__ float scratch[4][DIM];    // 2048 B: score partials / agg partials
    __shared__ float att_lds[KN];        // 256 B
    __shared__ int   ni_lds[KN];         // 256 B
    // ~37.9 KB -> 4 blocks/CU

    const int b   = blockIdx.x;
    const int m   = blockIdx.y;
    const int tid = threadIdx.x;
    const int len = neigh_len[b];
    const int nd  = node_idx[b];
    const float* __restrict__ emb = m ? emb_t : emb_v;

    // ---- pre-phase: u row + passthrough (+ len==0 fallback); ni ----
    if (tid < DIM) {
        float uv = emb[(size_t)nd * DIM + tid];
        out[((size_t)m * NB + b) * DIM + tid] = uv;
        if (len == 0)
            out[((size_t)(2 + m) * NB + b) * DIM + tid] = uv;
        u_lds[tid] = uv;
    } else if (tid < DIM + KN) {
        ni_lds[tid - DIM] = neigh_idx[b * KN + (tid - DIM)];
    }
    if (len == 0) return;   // block-uniform
    __syncthreads();   // B0: u_lds, ni ready

    const int wv = tid >> 6;
    const int ll = tid & 15;
    const int lh = (tid >> 4) & 3;
    const int nkt = (len + 15) >> 4;   // 1..4, block-uniform
    const int lim = nkt * 16;
    const f32x4 zero4 = {0.f, 0.f, 0.f, 0.f};

    // ---- gather valid neighbor rows -> bf16 LDS; uq partials overlap the latency ----
    for (int c = tid; c < lim * 16; c += 256) {
        int r = c >> 4, c8 = c & 15;
        bf16x8 v;
        if (r < len) {
            const float* src = emb + (size_t)ni_lds[r] * DIM + c8 * 8;
            float4 f0 = ((const float4*)src)[0];
            float4 f1 = ((const float4*)src)[1];
            v[0] = (bf16)f0.x; v[1] = (bf16)f0.y; v[2] = (bf16)f0.z; v[3] = (bf16)f0.w;
            v[4] = (bf16)f1.x; v[5] = (bf16)f1.y; v[6] = (bf16)f1.z; v[7] = (bf16)f1.w;
        } else {
            #pragma unroll
            for (int q = 0; q < 8; ++q) v[q] = (bf16)0.f;
        }
        *(bf16x8*)&n_lds[r][c8 * 8] = v;
    }
    {
        // uq partial: part[h][j] = sum_{i in h-half} u[i] * w1[128+i][j]
        int j = tid & 127, h = tid >> 7;
        const bf16* wb = w1T + (size_t)j * 256 + DIM + h * 64;
        const float* us = &u_lds[h * 64];
        float a = 0.f;
        #pragma unroll
        for (int i = 0; i < 64; i += 8) {
            bf16x8 w = *(const bf16x8*)(wb + i);
            #pragma unroll
            for (int q = 0; q < 8; ++q) a = fmaf(us[i + q], (float)w[q], a);
        }
        part_lds[h][j] = a;
    }
    __syncthreads();   // B1: n_lds + uq partials ready

    // ---- GEMM1 (j-split): H1^T = W1top^T @ N^T, +uq+b1 in epilogue, relu ----
    {
        bf16x8 af0[4], af1[4];
        #pragma unroll
        for (int ks = 0; ks < 4; ++ks) {
            af0[ks] = *(const bf16x8*)(w1T + (size_t)(wv * 32 + ll) * 256 + ks * 32 + lh * 8);
            af1[ks] = *(const bf16x8*)(w1T + (size_t)(wv * 32 + 16 + ll) * 256 + ks * 32 + lh * 8);
        }
        float4 b1q0 = *(const float4*)(b1 + wv * 32 + lh * 4);
        float4 b1q1 = *(const float4*)(b1 + wv * 32 + 16 + lh * 4);
        float4 p0a = *(const float4*)&part_lds[0][wv * 32 + lh * 4];
        float4 p1a = *(const float4*)&part_lds[1][wv * 32 + lh * 4];
        float4 p0b = *(const float4*)&part_lds[0][wv * 32 + 16 + lh * 4];
        float4 p1b = *(const float4*)&part_lds[1][wv * 32 + 16 + lh * 4];
        float uq0[4] = {p0a.x + p1a.x + b1q0.x, p0a.y + p1a.y + b1q0.y,
                        p0a.z + p1a.z + b1q0.z, p0a.w + p1a.w + b1q0.w};
        float uq1[4] = {p0b.x + p1b.x + b1q1.x, p0b.y + p1b.y + b1q1.y,
                        p0b.z + p1b.z + b1q1.z, p0b.w + p1b.w + b1q1.w};

        #pragma unroll
        for (int kt = 0; kt < 4; ++kt) {
            if (kt < nkt) {
                bf16x8 bfr[4];
                #pragma unroll
                for (int ks = 0; ks < 4; ++ks)
                    bfr[ks] = *(const bf16x8*)&n_lds[kt * 16 + ll][ks * 32 + lh * 8];
                f32x4 a0 = zero4, a1 = zero4;
                #pragma unroll
                for (int ks = 0; ks < 4; ++ks) {
                    a0 = __builtin_amdgcn_mfma_f32_16x16x32_bf16(af0[ks], bfr[ks], a0, 0, 0, 0);
                    a1 = __builtin_amdgcn_mfma_f32_16x16x32_bf16(af1[ks], bfr[ks], a1, 0, 0, 0);
                }
                bf16x4 h0, h1v;
                #pragma unroll
                for (int r = 0; r < 4; ++r) {
                    h0[r]  = (bf16)fmaxf(a0[r] + uq0[r], 0.f);
                    h1v[r] = (bf16)fmaxf(a1[r] + uq1[r], 0.f);
                }
                *(bf16x4*)&h1_lds[kt * 16 + ll][wv * 32 + lh * 4]      = h0;
                *(bf16x4*)&h1_lds[kt * 16 + ll][wv * 32 + 16 + lh * 4] = h1v;
            }
        }
    }
    __syncthreads();   // B2: h1 ready

    // ---- GEMM2 (j2-split): fused bias+relu+score partials ----
    {
        bf16x8 af20[4], af21[4];
        #pragma unroll
        for (int ks = 0; ks < 4; ++ks) {
            af20[ks] = *(const bf16x8*)(w2T + (size_t)(wv * 32 + ll) * 128 + ks * 32 + lh * 8);
            af21[ks] = *(const bf16x8*)(w2T + (size_t)(wv * 32 + 16 + ll) * 128 + ks * 32 + lh * 8);
        }
        float4 w3a = *(const float4*)(w3 + wv * 32 + lh * 4);
        float4 w3b = *(const float4*)(w3 + wv * 32 + 16 + lh * 4);
        float4 b2a = *(const float4*)(b2 + wv * 32 + lh * 4);
        float4 b2b = *(const float4*)(b2 + wv * 32 + 16 + lh * 4);
        float w3q0[4] = {w3a.x, w3a.y, w3a.z, w3a.w};
        float w3q1[4] = {w3b.x, w3b.y, w3b.z, w3b.w};
        float b2q0[4] = {b2a.x, b2a.y, b2a.z, b2a.w};
        float b2q1[4] = {b2b.x, b2b.y, b2b.z, b2b.w};

        #pragma unroll
        for (int ntk = 0; ntk < 4; ++ntk) {
            if (ntk < nkt) {
                bf16x8 bfr[4];
                #pragma unroll
                for (int ks = 0; ks < 4; ++ks)
                    bfr[ks] = *(const bf16x8*)&h1_lds[ntk * 16 + ll][ks * 32 + lh * 8];
                f32x4 c0 = zero4, c1 = zero4;
                #pragma unroll
                for (int ks = 0; ks < 4; ++ks) {
                    c0 = __builtin_amdgcn_mfma_f32_16x16x32_bf16(af20[ks], bfr[ks], c0, 0, 0, 0);
                    c1 = __builtin_amdgcn_mfma_f32_16x16x32_bf16(af21[ks], bfr[ks], c1, 0, 0, 0);
                }
                float s = 0.f;
                #pragma unroll
                for (int r = 0; r < 4; ++r) {
                    s = fmaf(fmaxf(c0[r] + b2q0[r], 0.f), w3q0[r], s);
                    s = fmaf(fmaxf(c1[r] + b2q1[r], 0.f), w3q1[r], s);
                }
                s += __shfl_xor(s, 16);
                s += __shfl_xor(s, 32);
                if (lh == 0) scratch[wv][ntk * 16 + ll] = s;
            }
        }
    }
    __syncthreads();   // B3: score partials ready

    // ---- masked softmax over neighbors (wave 0) ----
    if (tid < KN) {
        float s = scratch[0][tid] + scratch[1][tid] + scratch[2][tid] + scratch[3][tid];
        float sv = (tid < len) ? s : -INFINITY;
        float mx = sv;
        #pragma unroll
        for (int off = 1; off < 64; off <<= 1) mx = fmaxf(mx, __shfl_xor(mx, off));
        float e = (tid < len) ? __expf(sv - mx) : 0.f;
        float sum = e;
        #pragma unroll
        for (int off = 1; off < 64; off <<= 1) sum += __shfl_xor(sum, off);
        att_lds[tid] = e / sum;
    }
    __syncthreads();   // B4: att ready

    // ---- aggregate: agg[j] = sum_{k<len} att[k] * N[k][j] ----
    {
        int jg = tid & 31, ks = tid >> 5;   // per wave: ks in {2w, 2w+1}
        int j0 = jg * 4;
        float ax = 0.f, ay = 0.f, az = 0.f, aw = 0.f;
        int kb = ks * 8, ke = min(len, kb + 8);
        for (int k = kb; k < ke; ++k) {
            float av = att_lds[k];
            bf16x4 nv = *(const bf16x4*)&n_lds[k][j0];
            ax = fmaf(av, (float)nv[0], ax);
            ay = fmaf(av, (float)nv[1], ay);
            az = fmaf(av, (float)nv[2], az);
            aw = fmaf(av, (float)nv[3], aw);
        }
        ax += __shfl_xor(ax, 32);
        ay += __shfl_xor(ay, 32);
        az += __shfl_xor(az, 32);
        aw += __shfl_xor(aw, 32);
        if ((tid & 63) < 32) {
            float4 v4 = {ax, ay, az, aw};
            *(float4*)&scratch[wv][j0] = v4;
        }
    }
    __syncthreads();   // B5: agg partials ready
    if (tid < DIM)
        out[((size_t)(2 + m) * NB + b) * DIM + tid] =
            scratch[0][tid] + scratch[1][tid] + scratch[2][tid] + scratch[3][tid];
}

extern "C" void kernel_launch(void* const* d_in, const int* in_sizes, int n_in,
                              void* d_out, int out_size, void* d_ws, size_t ws_size,
                              hipStream_t stream) {
    const int*   node_idx  = (const int*)d_in[0];
    const int*   neigh_idx = (const int*)d_in[1];
    const int*   neigh_len = (const int*)d_in[2];
    const float* emb_v     = (const float*)d_in[3];
    const float* emb_t     = (const float*)d_in[4];
    const float* w1        = (const float*)d_in[5];
    const float* b1        = (const float*)d_in[6];
    const float* w2        = (const float*)d_in[7];
    const float* b2        = (const float*)d_in[8];
    const float* w3        = (const float*)d_in[9];
    float* out = (float*)d_out;

    bf16* w1T = (bf16*)d_ws;                 // 128*256 bf16 = 64 KiB
    bf16* w2T = (bf16*)d_ws + 128 * 256;     // 128*128 bf16 = 32 KiB

    hipLaunchKernelGGL(prep_weights, dim3(192), dim3(256), 0, stream, w1, w2, w1T, w2T);
    hipLaunchKernelGGL(graphsage_mfma, dim3(NB, 2), dim3(256), 0, stream,
                       node_idx, neigh_idx, neigh_len, emb_v, emb_t,
                       w1T, b1, w2T, b2, w3, out);
}